// Round 7
// baseline (622.626 us; speedup 1.0000x reference)
//
#include <hip/hip_runtime.h>
#include <hip/hip_cooperative_groups.h>
#include <cstdint>
#include <cstddef>
#include <cmath>

namespace cg = cooperative_groups;

#define BS 64
#define SEQ 1024
#define IN_DIM 512
#define EMB 1024
#define HID 512
#define KSEL 306
#define MROWS (BS * KSEL)  // 19584 = 153 * 128

typedef __bf16 bf16_t;
typedef bf16_t bf16x8 __attribute__((ext_vector_type(8)));
typedef bf16_t bf16x4 __attribute__((ext_vector_type(4)));
typedef float f32x4 __attribute__((ext_vector_type(4)));

__device__ __forceinline__ void async16(const void* g, void* l) {
  __builtin_amdgcn_global_load_lds(
      (const __attribute__((address_space(1))) unsigned int*)g,
      (__attribute__((address_space(3))) unsigned int*)l, 16, 0, 0);
}

// float atomic max via signed-max / unsigned-min trick (no NaNs present).
__device__ __forceinline__ void atomicMaxF(float* a, float v) {
  if (v >= 0.f)
    atomicMax((int*)a, __float_as_int(v));
  else
    atomicMin((unsigned int*)a, __float_as_uint(v));
}

// ---------- meta: eos position per batch; init out to -inf ----------
__global__ void k_meta(const int* __restrict__ text, int* __restrict__ eos,
                       float* __restrict__ out) {
  int b = blockIdx.x;
  __shared__ int cnt;
  if (threadIdx.x == 0) cnt = 0;
  __syncthreads();
  int local = 0;
  for (int i = threadIdx.x; i < SEQ; i += blockDim.x)
    local += (text[b * SEQ + i] != 0) ? 1 : 0;
  atomicAdd(&cnt, local);
  for (int c = threadIdx.x; c < EMB; c += blockDim.x)
    out[(b << 10) + c] = -INFINITY;
  __syncthreads();
  if (threadIdx.x == 0) {
    int L = cnt > 1 ? cnt : 1;
    int e = L - 1;
    if (e > SEQ - 1) e = SEQ - 1;
    eos[b] = e;
  }
}

// ---------- column exp-sum partials (softmax denominator), no atomics ----------
__global__ void k_colsum(const float* __restrict__ atten, float* __restrict__ part) {
  int b = blockIdx.x;
  int r0 = blockIdx.y << 6;
  int c = threadIdx.x << 2;
  const float* base = atten + ((size_t)b << 20) + ((size_t)r0 << 10) + c;
  float4 s = {0.f, 0.f, 0.f, 0.f};
#pragma unroll 4
  for (int r = 0; r < 64; ++r) {
    float4 x = *(const float4*)(base + ((size_t)r << 10));
    s.x += __expf((isfinite(x.x) ? x.x : 0.f) - 12.f);
    s.y += __expf((isfinite(x.y) ? x.y : 0.f) - 12.f);
    s.z += __expf((isfinite(x.z) ? x.z : 0.f) - 12.f);
    s.w += __expf((isfinite(x.w) ? x.w : 0.f) - 12.f);
  }
  *(float4*)&part[((((size_t)blockIdx.y << 6) | b) << 10) | c] = s;
}

// ---------- fused selval + top-K by rank counting (tie-break: lower idx) ----------
// grid (BS, 4) x 256. Each block recomputes the full 1024-col selval row into LDS
// (deterministic, identical across the 4 blocks of a batch), then ranks its quarter.
__global__ void k_topk(const float* __restrict__ atten, const int* __restrict__ text,
                       const int* __restrict__ eos, const float* __restrict__ part,
                       int* __restrict__ selidx) {
  int b = blockIdx.x;
  __shared__ float vals[SEQ];
  int e = eos[b];
  for (int c = threadIdx.x; c < SEQ; c += 256) {
    float cs = 0.f;
#pragma unroll
    for (int p = 0; p < 16; ++p) cs += part[(((p << 6) | b) << 10) | c];
    float v = atten[((size_t)b << 20) + ((size_t)e << 10) + c];
    if (!isfinite(v)) v = 0.f;
    int tok = text[(b << 10) | c];
    float res;
    if (tok == 0) res = 0.f;
    else if (c == 0 || c == e) res = 1.f / 1024.f;  // fully-masked column -> uniform
    else res = __expf(v - 12.f) / cs;
    vals[c] = res;
  }
  __syncthreads();
  int i = (blockIdx.y << 8) | threadIdx.x;
  float vc = vals[i];
  int rank = 0;
  for (int j = 0; j < SEQ; ++j) {
    float vj = vals[j];
    rank += (vj > vc || (vj == vc && j < i)) ? 1 : 0;
  }
  if (rank < KSEL) selidx[b * KSEL + rank] = i;
}

// ---------- gather selected rows + L2 normalize -> bf16 into xcat[:, 0:512] ----------
__global__ void k_gather(const float* __restrict__ features, const int* __restrict__ sel,
                         bf16_t* __restrict__ xcat) {
  int row = blockIdx.x;  // 0..MROWS-1
  int b = row / KSEL;
  int k = row - b * KSEL;
  int idx = sel[b * KSEL + k];
  const float4* src = (const float4*)(features + (((size_t)b << 10) + idx) * IN_DIM);
  float4 v = src[threadIdx.x];  // 128 threads * float4 = 512
  float ss = v.x * v.x + v.y * v.y + v.z * v.z + v.w * v.w;
#pragma unroll
  for (int off = 32; off > 0; off >>= 1) ss += __shfl_down(ss, off, 64);
  __shared__ float wsum[2];
  int lane = threadIdx.x & 63, wid = threadIdx.x >> 6;
  if (lane == 0) wsum[wid] = ss;
  __syncthreads();
  float total = wsum[0] + wsum[1];
  float scale = 1.f / fmaxf(sqrtf(total), 1e-6f);
  bf16x4 o;
  o[0] = (bf16_t)(v.x * scale);
  o[1] = (bf16_t)(v.y * scale);
  o[2] = (bf16_t)(v.z * scale);
  o[3] = (bf16_t)(v.w * scale);
  *(bf16x4*)(xcat + (size_t)row * EMB + (threadIdx.x << 2)) = o;
}

// ---------- all 3 weight transposes (f32->bf16) in one launch ----------
// by<16: w1(512x512)->w1t ; 16<=by<48: lin_w(512x1024)->wcatt[:, :] rows,
// by>=48: w2(512x1024)->wcatt cols 512.. (dst row n, col 512+k).
__global__ void k_transpose_all(const float* __restrict__ w1, const float* __restrict__ lin_w,
                                const float* __restrict__ w2, bf16_t* __restrict__ w1t,
                                bf16_t* __restrict__ wcatt) {
  __shared__ float tile[32][33];
  int by = blockIdx.y;
  const float* src; int srcld; bf16_t* dst; int dstld; int n0;
  if (by < 16)      { src = w1;    srcld = HID; dst = w1t;         dstld = IN_DIM; n0 = by << 5; }
  else if (by < 48) { src = lin_w; srcld = EMB; dst = wcatt;       dstld = EMB;    n0 = (by - 16) << 5; }
  else              { src = w2;    srcld = EMB; dst = wcatt + 512; dstld = EMB;    n0 = (by - 48) << 5; }
  int k0 = blockIdx.x << 5;
  int tx = threadIdx.x, ty = threadIdx.y;
#pragma unroll
  for (int i = 0; i < 4; i++)
    tile[ty + 8 * i][tx] = src[(size_t)(k0 + ty + 8 * i) * srcld + n0 + tx];
  __syncthreads();
#pragma unroll
  for (int i = 0; i < 4; i++)
    dst[(size_t)(n0 + ty + 8 * i) * dstld + k0 + tx] = (bf16_t)tile[tx][ty + 8 * i];
}

// ---------- cooperative fused GEMM1 + BN stats + grid sync + BN apply + ReLU ----------
// grid = 153 blocks x 512 thr (1 block/CU -> co-residency guaranteed).
// Tile 128x512 (full N), 8 waves as 2Mx4N of 64x128 each.
// Phase 1: acc = xcat[:, :512] @ w1t^T + b1 ; column sum/sumsq atomics into stats.
// grid.sync() ; Phase 2: read stats, BN-affine + ReLU on held f32 acc, write bf16
// into xcat[:, 512:1024]. h is never materialized.
__global__ __launch_bounds__(512, 1) void k_gemm1_coop(
    const bf16_t* A,                    // xcat (reads cols 0..511)
    const bf16_t* __restrict__ Bt,      // w1t, ldb = IN_DIM
    const float* __restrict__ b1, const float* __restrict__ g1,
    const float* __restrict__ be1, float* stats,
    bf16_t* xcat_out) {                 // xcat (writes cols 512..1023)
  __shared__ __align__(16) bf16_t As[128 * 32];
  __shared__ __align__(16) bf16_t Bs[512 * 32];
  int tid = threadIdx.x;
  int m0 = blockIdx.x << 7;
  int wave = tid >> 6, lane = tid & 63;
  int wm = (wave >> 2) << 6;   // 0 or 64
  int wn = (wave & 3) << 7;    // 0,128,256,384
  int lrow = lane & 15, quad = lane >> 4;

  f32x4 acc[4][8];
#pragma unroll
  for (int i = 0; i < 4; i++)
#pragma unroll
    for (int j = 0; j < 8; j++) acc[i][j] = (f32x4){0.f, 0.f, 0.f, 0.f};

  // A: 512 chunks of 16B (128 rows x 4 k-chunks); one per thread.
  int arow = tid >> 2, ak = (tid & 3) << 3;
  const bf16_t* Ap = A + (size_t)(m0 + arow) * EMB + ak;
  // B: 2048 chunks (512 rows x 4); 4 per thread at +512 stride.
  int brow0 = tid >> 2, bk = (tid & 3) << 3;
  const bf16_t* Bp0 = Bt + (size_t)(brow0 + 0) * IN_DIM + bk;
  const bf16_t* Bp1 = Bt + (size_t)(brow0 + 128) * IN_DIM + bk;
  const bf16_t* Bp2 = Bt + (size_t)(brow0 + 256) * IN_DIM + bk;
  const bf16_t* Bp3 = Bt + (size_t)(brow0 + 384) * IN_DIM + bk;

  for (int k0 = 0; k0 < IN_DIM; k0 += 32) {
    async16(Ap + k0, &As[tid << 3]);
    async16(Bp0 + k0, &Bs[(tid + 0) << 3]);
    async16(Bp1 + k0, &Bs[(tid + 512) << 3]);
    async16(Bp2 + k0, &Bs[(tid + 1024) << 3]);
    async16(Bp3 + k0, &Bs[(tid + 1536) << 3]);
    __syncthreads();

    bf16x8 af[4], bfr[8];
#pragma unroll
    for (int i = 0; i < 4; i++)
      af[i] = *(const bf16x8*)&As[((wm + (i << 4) + lrow) << 5) + (quad << 3)];
#pragma unroll
    for (int j = 0; j < 8; j++)
      bfr[j] = *(const bf16x8*)&Bs[((wn + (j << 4) + lrow) << 5) + (quad << 3)];
#pragma unroll
    for (int i = 0; i < 4; i++)
#pragma unroll
      for (int j = 0; j < 8; j++)
        acc[i][j] = __builtin_amdgcn_mfma_f32_16x16x32_bf16(af[i], bfr[j], acc[i][j], 0, 0, 0);
    __syncthreads();
  }

  // bias + BN stats (C/D layout: col = lane&15, row = quad*4 + reg)
#pragma unroll
  for (int j = 0; j < 8; j++) {
    int n = wn + (j << 4) + lrow;  // 0..511 (full N in one block)
    float bv = b1[n];
    float s = 0.f, qq = 0.f;
#pragma unroll
    for (int i = 0; i < 4; i++) {
#pragma unroll
      for (int rr = 0; rr < 4; rr++) {
        float v = acc[i][j][rr] + bv;
        acc[i][j][rr] = v;  // keep biased value for phase 2
        s += v;
        qq += v * v;
      }
    }
    s += __shfl_xor(s, 16, 64);
    s += __shfl_xor(s, 32, 64);
    qq += __shfl_xor(qq, 16, 64);
    qq += __shfl_xor(qq, 32, 64);
    if (quad == 0) {
      atomicAdd(&stats[n], s);
      atomicAdd(&stats[HID + n], qq);
    }
  }

  cg::this_grid().sync();

  const float inv = 1.f / (float)MROWS;
#pragma unroll
  for (int j = 0; j < 8; j++) {
    int n = wn + (j << 4) + lrow;
    float mu = stats[n] * inv;
    float var = fmaxf(stats[HID + n] * inv - mu * mu, 0.f);  // biased var
    float sc = g1[n] * rsqrtf(var + 1e-5f);
    float sh = fmaf(-mu, sc, be1[n]);
#pragma unroll
    for (int i = 0; i < 4; i++) {
      int mbase = m0 + wm + (i << 4) + (quad << 2);
#pragma unroll
      for (int rr = 0; rr < 4; rr++) {
        float a = fmaxf(fmaf(acc[i][j][rr], sc, sh), 0.f);
        xcat_out[(size_t)(mbase + rr) * EMB + 512 + n] = (bf16_t)a;
      }
    }
  }
}

// ---------- GEMM2: fused = xcat @ wcatt^T + (lin_b+b2), fused per-batch max-pool ----------
// 128x128 tile, 4 waves; XCD-bijective swizzle (n-fastest) for A-panel L2 residency.
__global__ __launch_bounds__(256, 2) void k_gemm2(
    const bf16_t* __restrict__ A, const bf16_t* __restrict__ Bt,
    const float* __restrict__ lin_b, const float* __restrict__ b2,
    float* __restrict__ outmax) {
  __shared__ __align__(16) bf16_t As[128 * 32];
  __shared__ __align__(16) bf16_t Bs[128 * 32];
  int tid = threadIdx.x;

  int MT = gridDim.x, NT = gridDim.y;
  int nwg = MT * NT;
  int flat = blockIdx.y * MT + blockIdx.x;
  int q = nwg >> 3, r = nwg & 7;
  int xcd = flat & 7, ii = flat >> 3;
  int lin = (xcd < r ? xcd * (q + 1) : r * (q + 1) + (xcd - r) * q) + ii;
  int mtile = lin / NT;
  int ntile = lin - mtile * NT;
  int m0 = mtile << 7, n0 = ntile << 7;

  int wave = tid >> 6, lane = tid & 63;
  int wm = (wave >> 1) << 6, wn = (wave & 1) << 6;
  int lrow = lane & 15, quad = lane >> 4;

  f32x4 acc[4][4];
#pragma unroll
  for (int i = 0; i < 4; i++)
#pragma unroll
    for (int j = 0; j < 4; j++) acc[i][j] = (f32x4){0.f, 0.f, 0.f, 0.f};

  int c0 = tid, c1 = 256 + tid;
  int ar0 = c0 >> 2, ak0 = (c0 & 3) << 3;
  int ar1 = c1 >> 2, ak1 = (c1 & 3) << 3;
  const bf16_t* Ap0 = A + (size_t)(m0 + ar0) * EMB + ak0;
  const bf16_t* Ap1 = A + (size_t)(m0 + ar1) * EMB + ak1;
  const bf16_t* Bp0 = Bt + (size_t)(n0 + ar0) * EMB + ak0;
  const bf16_t* Bp1 = Bt + (size_t)(n0 + ar1) * EMB + ak1;

  for (int k0 = 0; k0 < EMB; k0 += 32) {
    async16(Ap0 + k0, &As[c0 << 3]);
    async16(Ap1 + k0, &As[c1 << 3]);
    async16(Bp0 + k0, &Bs[c0 << 3]);
    async16(Bp1 + k0, &Bs[c1 << 3]);
    __syncthreads();

    bf16x8 af[4], bfr[4];
#pragma unroll
    for (int i = 0; i < 4; i++)
      af[i] = *(const bf16x8*)&As[((wm + (i << 4) + lrow) << 5) + (quad << 3)];
#pragma unroll
    for (int j = 0; j < 4; j++)
      bfr[j] = *(const bf16x8*)&Bs[((wn + (j << 4) + lrow) << 5) + (quad << 3)];
#pragma unroll
    for (int i = 0; i < 4; i++)
#pragma unroll
      for (int j = 0; j < 4; j++)
        acc[i][j] = __builtin_amdgcn_mfma_f32_16x16x32_bf16(af[i], bfr[j], acc[i][j], 0, 0, 0);
    __syncthreads();
  }

  int mw = m0 + wm;          // wave covers rows mw .. mw+63
  int b0w = mw / KSEL;       // tile spans <= 2 batches (64 < 306)
  int cut = (b0w + 1) * KSEL;
#pragma unroll
  for (int j = 0; j < 4; j++) {
    int n = n0 + wn + (j << 4) + lrow;
    float bv = lin_b[n] + b2[n];
    float mx0 = -INFINITY, mx1 = -INFINITY;
#pragma unroll
    for (int i = 0; i < 4; i++) {
#pragma unroll
      for (int rr = 0; rr < 4; rr++) {
        int m = mw + (i << 4) + (quad << 2) + rr;
        float v = acc[i][j][rr] + bv;
        if (m < cut) mx0 = fmaxf(mx0, v);
        else mx1 = fmaxf(mx1, v);
      }
    }
    mx0 = fmaxf(mx0, __shfl_xor(mx0, 16, 64));
    mx0 = fmaxf(mx0, __shfl_xor(mx0, 32, 64));
    mx1 = fmaxf(mx1, __shfl_xor(mx1, 16, 64));
    mx1 = fmaxf(mx1, __shfl_xor(mx1, 32, 64));
    if (quad == 0) {
      atomicMaxF(&outmax[(b0w << 10) + n], mx0);
      if (cut < mw + 64) atomicMaxF(&outmax[((b0w + 1) << 10) + n], mx1);
    }
  }
}

extern "C" void kernel_launch(void* const* d_in, const int* in_sizes, int n_in,
                              void* d_out, int out_size, void* d_ws, size_t ws_size,
                              hipStream_t stream) {
  const float* features = (const float*)d_in[0];
  const float* atten    = (const float*)d_in[1];
  const int*   text     = (const int*)d_in[2];
  const float* lin_w    = (const float*)d_in[3];
  const float* lin_b    = (const float*)d_in[4];
  const float* w1       = (const float*)d_in[5];
  const float* b1       = (const float*)d_in[6];
  const float* g1       = (const float*)d_in[7];
  const float* be1      = (const float*)d_in[8];
  const float* w2       = (const float*)d_in[9];
  const float* b2       = (const float*)d_in[10];
  float* out = (float*)d_out;

  char* ws = (char*)d_ws;
  int*    eos    = (int*)(ws + 0);               // 64 int
  float*  stats  = (float*)(ws + 256);           // 1024 f32
  float*  part   = (float*)(ws + 8192);          // 16*64*1024 f32 (4 MB)
  int*    selidx = (int*)(ws + 4202496UL);       // 64*306 int
  bf16_t* w1t    = (bf16_t*)(ws + 4280832UL);    // 512*512 bf16
  bf16_t* wcatt  = (bf16_t*)(ws + 4805120UL);    // 1024*1024 bf16
  bf16_t* xcat   = (bf16_t*)(ws + 6902272UL);    // 19584*1024 bf16 (40 MB)
  // total: 47,010,304 bytes

  hipMemsetAsync(stats, 0, 4096, stream);

  k_meta<<<BS, 256, 0, stream>>>(text, eos, out);
  k_colsum<<<dim3(BS, 16), 256, 0, stream>>>(atten, part);
  k_topk<<<dim3(BS, 4), 256, 0, stream>>>(atten, text, eos, part, selidx);
  k_gather<<<MROWS, 128, 0, stream>>>(features, selidx, xcat);
  k_transpose_all<<<dim3(16, 80), dim3(32, 8), 0, stream>>>(w1, lin_w, w2, w1t, wcatt);

  // fused GEMM1 + BN (cooperative, grid=153 = 1 block/CU)
  {
    const bf16_t* gA = xcat;
    const bf16_t* gB = w1t;
    const float* gb1 = b1;
    const float* gg1 = g1;
    const float* gbe = be1;
    float* gst = stats;
    bf16_t* gx = xcat;
    void* kargs[] = {(void*)&gA, (void*)&gB, (void*)&gb1, (void*)&gg1,
                     (void*)&gbe, (void*)&gst, (void*)&gx};
    hipLaunchCooperativeKernel((void*)k_gemm1_coop, dim3(MROWS / 128), dim3(512),
                               kargs, 0, stream);
  }

  // GEMM2: fused = [xf | relu(bn(h))] @ [lin_w ; w2] + (lin_b+b2), fused max-pool
  k_gemm2<<<dim3(MROWS / 128, EMB / 128), 256, 0, stream>>>(
      xcat, wcatt, lin_b, b2, out);
}

// Round 9
// 571.167 us; speedup vs baseline: 1.0901x; 1.0901x over previous
//
#include <hip/hip_runtime.h>
#include <cstdint>
#include <cstddef>
#include <cmath>

#define BS 64
#define SEQ 1024
#define IN_DIM 512
#define EMB 1024
#define HID 512
#define KSEL 306
#define MROWS (BS * KSEL)  // 19584 = 153 * 128

typedef __bf16 bf16_t;
typedef bf16_t bf16x8 __attribute__((ext_vector_type(8)));
typedef bf16_t bf16x4 __attribute__((ext_vector_type(4)));
typedef float f32x4 __attribute__((ext_vector_type(4)));

__device__ __forceinline__ void async16(const void* g, void* l) {
  __builtin_amdgcn_global_load_lds(
      (const __attribute__((address_space(1))) unsigned int*)g,
      (__attribute__((address_space(3))) unsigned int*)l, 16, 0, 0);
}

// float atomic max via signed-max / unsigned-min trick (no NaNs present).
__device__ __forceinline__ void atomicMaxF(float* a, float v) {
  if (v >= 0.f)
    atomicMax((int*)a, __float_as_int(v));
  else
    atomicMin((unsigned int*)a, __float_as_uint(v));
}

// ---------- meta: eos position per batch; init out to -inf ----------
__global__ void k_meta(const int* __restrict__ text, int* __restrict__ eos,
                       float* __restrict__ out) {
  int b = blockIdx.x;
  __shared__ int cnt;
  if (threadIdx.x == 0) cnt = 0;
  __syncthreads();
  int local = 0;
  for (int i = threadIdx.x; i < SEQ; i += blockDim.x)
    local += (text[b * SEQ + i] != 0) ? 1 : 0;
  atomicAdd(&cnt, local);
  for (int c = threadIdx.x; c < EMB; c += blockDim.x)
    out[(b << 10) + c] = -INFINITY;
  __syncthreads();
  if (threadIdx.x == 0) {
    int L = cnt > 1 ? cnt : 1;
    int e = L - 1;
    if (e > SEQ - 1) e = SEQ - 1;
    eos[b] = e;
  }
}

// ---------- column exp-sum partials (softmax denominator), no atomics ----------
__global__ void k_colsum(const float* __restrict__ atten, float* __restrict__ part) {
  int b = blockIdx.x;
  int r0 = blockIdx.y << 6;
  int c = threadIdx.x << 2;
  const float* base = atten + ((size_t)b << 20) + ((size_t)r0 << 10) + c;
  float4 s = {0.f, 0.f, 0.f, 0.f};
#pragma unroll 4
  for (int r = 0; r < 64; ++r) {
    float4 x = *(const float4*)(base + ((size_t)r << 10));
    s.x += __expf((isfinite(x.x) ? x.x : 0.f) - 12.f);
    s.y += __expf((isfinite(x.y) ? x.y : 0.f) - 12.f);
    s.z += __expf((isfinite(x.z) ? x.z : 0.f) - 12.f);
    s.w += __expf((isfinite(x.w) ? x.w : 0.f) - 12.f);
  }
  *(float4*)&part[((((size_t)blockIdx.y << 6) | b) << 10) | c] = s;
}

// ---------- fused selval + top-K by rank counting (tie-break: lower idx) ----------
// grid (BS, 4) x 256. Each block recomputes the full 1024-col selval row into LDS
// (deterministic, identical across the 4 blocks of a batch), then ranks its quarter.
__global__ void k_topk(const float* __restrict__ atten, const int* __restrict__ text,
                       const int* __restrict__ eos, const float* __restrict__ part,
                       int* __restrict__ selidx) {
  int b = blockIdx.x;
  __shared__ float vals[SEQ];
  int e = eos[b];
  for (int c = threadIdx.x; c < SEQ; c += 256) {
    float cs = 0.f;
#pragma unroll
    for (int p = 0; p < 16; ++p) cs += part[(((p << 6) | b) << 10) | c];
    float v = atten[((size_t)b << 20) + ((size_t)e << 10) + c];
    if (!isfinite(v)) v = 0.f;
    int tok = text[(b << 10) | c];
    float res;
    if (tok == 0) res = 0.f;
    else if (c == 0 || c == e) res = 1.f / 1024.f;  // fully-masked column -> uniform
    else res = __expf(v - 12.f) / cs;
    vals[c] = res;
  }
  __syncthreads();
  int i = (blockIdx.y << 8) | threadIdx.x;
  float vc = vals[i];
  int rank = 0;
  for (int j = 0; j < SEQ; ++j) {
    float vj = vals[j];
    rank += (vj > vc || (vj == vc && j < i)) ? 1 : 0;
  }
  if (rank < KSEL) selidx[b * KSEL + rank] = i;
}

// ---------- gather selected rows + L2 normalize -> bf16 into xcat[:, 0:512] ----------
__global__ void k_gather(const float* __restrict__ features, const int* __restrict__ sel,
                         bf16_t* __restrict__ xcat) {
  int row = blockIdx.x;  // 0..MROWS-1
  int b = row / KSEL;
  int k = row - b * KSEL;
  int idx = sel[b * KSEL + k];
  const float4* src = (const float4*)(features + (((size_t)b << 10) + idx) * IN_DIM);
  float4 v = src[threadIdx.x];  // 128 threads * float4 = 512
  float ss = v.x * v.x + v.y * v.y + v.z * v.z + v.w * v.w;
#pragma unroll
  for (int off = 32; off > 0; off >>= 1) ss += __shfl_down(ss, off, 64);
  __shared__ float wsum[2];
  int lane = threadIdx.x & 63, wid = threadIdx.x >> 6;
  if (lane == 0) wsum[wid] = ss;
  __syncthreads();
  float total = wsum[0] + wsum[1];
  float scale = 1.f / fmaxf(sqrtf(total), 1e-6f);
  bf16x4 o;
  o[0] = (bf16_t)(v.x * scale);
  o[1] = (bf16_t)(v.y * scale);
  o[2] = (bf16_t)(v.z * scale);
  o[3] = (bf16_t)(v.w * scale);
  *(bf16x4*)(xcat + (size_t)row * EMB + (threadIdx.x << 2)) = o;
}

// ---------- all 3 weight transposes (f32->bf16) in one launch ----------
__global__ void k_transpose_all(const float* __restrict__ w1, const float* __restrict__ lin_w,
                                const float* __restrict__ w2, bf16_t* __restrict__ w1t,
                                bf16_t* __restrict__ wcatt) {
  __shared__ float tile[32][33];
  int by = blockIdx.y;
  const float* src; int srcld; bf16_t* dst; int dstld; int n0;
  if (by < 16)      { src = w1;    srcld = HID; dst = w1t;         dstld = IN_DIM; n0 = by << 5; }
  else if (by < 48) { src = lin_w; srcld = EMB; dst = wcatt;       dstld = EMB;    n0 = (by - 16) << 5; }
  else              { src = w2;    srcld = EMB; dst = wcatt + 512; dstld = EMB;    n0 = (by - 48) << 5; }
  int k0 = blockIdx.x << 5;
  int tx = threadIdx.x, ty = threadIdx.y;
#pragma unroll
  for (int i = 0; i < 4; i++)
    tile[ty + 8 * i][tx] = src[(size_t)(k0 + ty + 8 * i) * srcld + n0 + tx];
  __syncthreads();
#pragma unroll
  for (int i = 0; i < 4; i++)
    dst[(size_t)(n0 + ty + 8 * i) * dstld + k0 + tx] = (bf16_t)tile[tx][ty + 8 * i];
}

// ---------- GEMM1: h(bf16) = xcat[:, :512] @ w1t^T + b1, fused BN stats ----------
// 128x128 tile, 4 waves, XCD-bijective swizzle; grid (153,4) = 612 blocks (all CUs).
__global__ __launch_bounds__(256, 2) void k_gemm1(
    const bf16_t* __restrict__ A, const bf16_t* __restrict__ Bt,
    const float* __restrict__ b1, bf16_t* __restrict__ C,
    float* __restrict__ stats) {
  __shared__ __align__(16) bf16_t As[128 * 32];
  __shared__ __align__(16) bf16_t Bs[128 * 32];
  int tid = threadIdx.x;

  int MT = gridDim.x, NT = gridDim.y;
  int nwg = MT * NT;
  int flat = blockIdx.y * MT + blockIdx.x;
  int q = nwg >> 3, r = nwg & 7;
  int xcd = flat & 7, ii = flat >> 3;
  int lin = (xcd < r ? xcd * (q + 1) : r * (q + 1) + (xcd - r) * q) + ii;
  int mtile = lin / NT;
  int ntile = lin - mtile * NT;
  int m0 = mtile << 7, n0 = ntile << 7;

  int wave = tid >> 6, lane = tid & 63;
  int wm = (wave >> 1) << 6, wn = (wave & 1) << 6;
  int lrow = lane & 15, quad = lane >> 4;

  f32x4 acc[4][4];
#pragma unroll
  for (int i = 0; i < 4; i++)
#pragma unroll
    for (int j = 0; j < 4; j++) acc[i][j] = (f32x4){0.f, 0.f, 0.f, 0.f};

  int c0 = tid, c1 = 256 + tid;
  int ar0 = c0 >> 2, ak0 = (c0 & 3) << 3;
  int ar1 = c1 >> 2, ak1 = (c1 & 3) << 3;
  const bf16_t* Ap0 = A + (size_t)(m0 + ar0) * EMB + ak0;
  const bf16_t* Ap1 = A + (size_t)(m0 + ar1) * EMB + ak1;
  const bf16_t* Bp0 = Bt + (size_t)(n0 + ar0) * IN_DIM + ak0;
  const bf16_t* Bp1 = Bt + (size_t)(n0 + ar1) * IN_DIM + ak1;

  for (int k0 = 0; k0 < IN_DIM; k0 += 32) {
    async16(Ap0 + k0, &As[c0 << 3]);
    async16(Ap1 + k0, &As[c1 << 3]);
    async16(Bp0 + k0, &Bs[c0 << 3]);
    async16(Bp1 + k0, &Bs[c1 << 3]);
    __syncthreads();

    bf16x8 af[4], bfr[4];
#pragma unroll
    for (int i = 0; i < 4; i++)
      af[i] = *(const bf16x8*)&As[((wm + (i << 4) + lrow) << 5) + (quad << 3)];
#pragma unroll
    for (int j = 0; j < 4; j++)
      bfr[j] = *(const bf16x8*)&Bs[((wn + (j << 4) + lrow) << 5) + (quad << 3)];
#pragma unroll
    for (int i = 0; i < 4; i++)
#pragma unroll
      for (int j = 0; j < 4; j++)
        acc[i][j] = __builtin_amdgcn_mfma_f32_16x16x32_bf16(af[i], bfr[j], acc[i][j], 0, 0, 0);
    __syncthreads();
  }

  // C/D layout: col = lane&15, row = quad*4 + reg
#pragma unroll
  for (int j = 0; j < 4; j++) {
    int n = n0 + wn + (j << 4) + lrow;
    float bv = b1[n];
    float s = 0.f, qq = 0.f;
#pragma unroll
    for (int i = 0; i < 4; i++) {
      int mbase = m0 + wm + (i << 4) + (quad << 2);
#pragma unroll
      for (int rr = 0; rr < 4; rr++) {
        float v = acc[i][j][rr] + bv;
        C[(size_t)(mbase + rr) * HID + n] = (bf16_t)v;
        s += v;
        qq += v * v;
      }
    }
    s += __shfl_xor(s, 16, 64);
    s += __shfl_xor(s, 32, 64);
    qq += __shfl_xor(qq, 16, 64);
    qq += __shfl_xor(qq, 32, 64);
    if (quad == 0) {
      atomicAdd(&stats[n], s);
      atomicAdd(&stats[HID + n], qq);
    }
  }
}

// BN params from stats (512 threads).
__global__ void k_bnparam(const float* __restrict__ stats, const float* __restrict__ g,
                          const float* __restrict__ be, float* __restrict__ scsh) {
  int c = threadIdx.x;
  float inv = 1.f / (float)MROWS;
  float mu = stats[c] * inv;
  float var = fmaxf(stats[HID + c] * inv - mu * mu, 0.f);  // biased var
  float sc = g[c] * rsqrtf(var + 1e-5f);
  scsh[c] = sc;
  scsh[HID + c] = fmaf(-mu, sc, be[c]);
}

// BN apply + ReLU on bf16 h, emit bf16 into xcat[:, 512:1024]
__global__ void k_bnapply(const bf16_t* __restrict__ h, const float* __restrict__ scsh,
                          bf16_t* __restrict__ xcat) {
  size_t idx = (size_t)blockIdx.x * blockDim.x + threadIdx.x;  // over MROWS*64
  bf16x8 x = ((const bf16x8*)h)[idx];
  int c = (int)(idx & 63) << 3;
  size_t row = idx >> 6;
  bf16x8 o;
#pragma unroll
  for (int t = 0; t < 8; ++t) {
    float v = (float)x[t];
    float a = fmaxf(fmaf(v, scsh[c + t], scsh[HID + c + t]), 0.f);
    o[t] = (bf16_t)a;
  }
  *(bf16x8*)(xcat + row * EMB + 512 + c) = o;
}

// ---------- GEMM2: fused = xcat @ wcatt^T + (lin_b+b2), fused per-batch max-pool ----------
__global__ __launch_bounds__(256, 2) void k_gemm2(
    const bf16_t* __restrict__ A, const bf16_t* __restrict__ Bt,
    const float* __restrict__ lin_b, const float* __restrict__ b2,
    float* __restrict__ outmax) {
  __shared__ __align__(16) bf16_t As[128 * 32];
  __shared__ __align__(16) bf16_t Bs[128 * 32];
  int tid = threadIdx.x;

  int MT = gridDim.x, NT = gridDim.y;
  int nwg = MT * NT;
  int flat = blockIdx.y * MT + blockIdx.x;
  int q = nwg >> 3, r = nwg & 7;
  int xcd = flat & 7, ii = flat >> 3;
  int lin = (xcd < r ? xcd * (q + 1) : r * (q + 1) + (xcd - r) * q) + ii;
  int mtile = lin / NT;
  int ntile = lin - mtile * NT;
  int m0 = mtile << 7, n0 = ntile << 7;

  int wave = tid >> 6, lane = tid & 63;
  int wm = (wave >> 1) << 6, wn = (wave & 1) << 6;
  int lrow = lane & 15, quad = lane >> 4;

  f32x4 acc[4][4];
#pragma unroll
  for (int i = 0; i < 4; i++)
#pragma unroll
    for (int j = 0; j < 4; j++) acc[i][j] = (f32x4){0.f, 0.f, 0.f, 0.f};

  int c0 = tid, c1 = 256 + tid;
  int ar0 = c0 >> 2, ak0 = (c0 & 3) << 3;
  int ar1 = c1 >> 2, ak1 = (c1 & 3) << 3;
  const bf16_t* Ap0 = A + (size_t)(m0 + ar0) * EMB + ak0;
  const bf16_t* Ap1 = A + (size_t)(m0 + ar1) * EMB + ak1;
  const bf16_t* Bp0 = Bt + (size_t)(n0 + ar0) * EMB + ak0;
  const bf16_t* Bp1 = Bt + (size_t)(n0 + ar1) * EMB + ak1;

  for (int k0 = 0; k0 < EMB; k0 += 32) {
    async16(Ap0 + k0, &As[c0 << 3]);
    async16(Ap1 + k0, &As[c1 << 3]);
    async16(Bp0 + k0, &Bs[c0 << 3]);
    async16(Bp1 + k0, &Bs[c1 << 3]);
    __syncthreads();

    bf16x8 af[4], bfr[4];
#pragma unroll
    for (int i = 0; i < 4; i++)
      af[i] = *(const bf16x8*)&As[((wm + (i << 4) + lrow) << 5) + (quad << 3)];
#pragma unroll
    for (int j = 0; j < 4; j++)
      bfr[j] = *(const bf16x8*)&Bs[((wn + (j << 4) + lrow) << 5) + (quad << 3)];
#pragma unroll
    for (int i = 0; i < 4; i++)
#pragma unroll
      for (int j = 0; j < 4; j++)
        acc[i][j] = __builtin_amdgcn_mfma_f32_16x16x32_bf16(af[i], bfr[j], acc[i][j], 0, 0, 0);
    __syncthreads();
  }

  int mw = m0 + wm;          // wave covers rows mw .. mw+63
  int b0w = mw / KSEL;       // tile spans <= 2 batches (64 < 306)
  int cut = (b0w + 1) * KSEL;
#pragma unroll
  for (int j = 0; j < 4; j++) {
    int n = n0 + wn + (j << 4) + lrow;
    float bv = lin_b[n] + b2[n];
    float mx0 = -INFINITY, mx1 = -INFINITY;
#pragma unroll
    for (int i = 0; i < 4; i++) {
#pragma unroll
      for (int rr = 0; rr < 4; rr++) {
        int m = mw + (i << 4) + (quad << 2) + rr;
        float v = acc[i][j][rr] + bv;
        if (m < cut) mx0 = fmaxf(mx0, v);
        else mx1 = fmaxf(mx1, v);
      }
    }
    mx0 = fmaxf(mx0, __shfl_xor(mx0, 16, 64));
    mx0 = fmaxf(mx0, __shfl_xor(mx0, 32, 64));
    mx1 = fmaxf(mx1, __shfl_xor(mx1, 16, 64));
    mx1 = fmaxf(mx1, __shfl_xor(mx1, 32, 64));
    if (quad == 0) {
      atomicMaxF(&outmax[(b0w << 10) + n], mx0);
      if (cut < mw + 64) atomicMaxF(&outmax[((b0w + 1) << 10) + n], mx1);
    }
  }
}

extern "C" void kernel_launch(void* const* d_in, const int* in_sizes, int n_in,
                              void* d_out, int out_size, void* d_ws, size_t ws_size,
                              hipStream_t stream) {
  const float* features = (const float*)d_in[0];
  const float* atten    = (const float*)d_in[1];
  const int*   text     = (const int*)d_in[2];
  const float* lin_w    = (const float*)d_in[3];
  const float* lin_b    = (const float*)d_in[4];
  const float* w1       = (const float*)d_in[5];
  const float* b1       = (const float*)d_in[6];
  const float* g1       = (const float*)d_in[7];
  const float* be1      = (const float*)d_in[8];
  const float* w2       = (const float*)d_in[9];
  const float* b2       = (const float*)d_in[10];
  float* out = (float*)d_out;

  char* ws = (char*)d_ws;
  int*    eos    = (int*)(ws + 0);               // 64 int
  float*  stats  = (float*)(ws + 256);           // 1024 f32
  float*  scsh   = (float*)(ws + 4608);          // 1024 f32
  float*  part   = (float*)(ws + 12800);         // 16*64*1024 f32 (4 MB)
  int*    selidx = (int*)(ws + 4207104UL);       // 64*306 int
  bf16_t* w1t    = (bf16_t*)(ws + 4285440UL);    // 512*512 bf16
  bf16_t* wcatt  = (bf16_t*)(ws + 4809728UL);    // 1024*1024 bf16
  bf16_t* xcat   = (bf16_t*)(ws + 6906880UL);    // 19584*1024 bf16 (40 MB)
  bf16_t* h      = (bf16_t*)(ws + 47014912UL);   // 19584*512 bf16 (20 MB)
  // total: 67,068,928 bytes

  hipMemsetAsync(stats, 0, 4096, stream);

  k_meta<<<BS, 256, 0, stream>>>(text, eos, out);
  k_colsum<<<dim3(BS, 16), 256, 0, stream>>>(atten, part);
  k_topk<<<dim3(BS, 4), 256, 0, stream>>>(atten, text, eos, part, selidx);
  k_gather<<<MROWS, 128, 0, stream>>>(features, selidx, xcat);
  k_transpose_all<<<dim3(16, 80), dim3(32, 8), 0, stream>>>(w1, lin_w, w2, w1t, wcatt);

  // GEMM1: h = xcat[:, :512] @ w1 + b1, fused BN stats (M=19584, N=512, K=512)
  k_gemm1<<<dim3(MROWS / 128, HID / 128), 256, 0, stream>>>(xcat, w1t, b1, h, stats);

  k_bnparam<<<1, HID, 0, stream>>>(stats, g1, be1, scsh);
  k_bnapply<<<(MROWS * (HID / 8)) / 256, 256, 0, stream>>>(h, scsh, xcat);

  // GEMM2: fused = [xf | relu(bn(h))] @ [lin_w ; w2] + (lin_b+b2), fused max-pool
  k_gemm2<<<dim3(MROWS / 128, EMB / 128), 256, 0, stream>>>(
      xcat, wcatt, lin_b, b2, out);
}